// Round 1
// baseline (210.478 us; speedup 1.0000x reference)
//
#include <hip/hip_runtime.h>
#include <hip/hip_bf16.h>

// Problem constants (from reference): B=1, C=64 in/out, N_NODES=16384,
// TWO_M=1048576 -> M=524288 edges.
#define C_DIM 64
#define N_NODES 16384
#define M_EDGES 524288

// out[:,n] = cnt[n] * (W0@seq)[:,n] + sum_{edges m with u_m==n} (W1@seq)[:, v_m]
// K1: P = W0@seq (into d_out, [o][n]) and Tt = (W1@seq)^T ([n][o]) for coalesced scatter.
// K2: scatter Tt[v] into outT[u] with fp32 HW atomics + int histogram cnt[u].
// K3: out[o][n] = outT[n][o] + cnt[n]*P[o][n]  (LDS tile transpose, in-place on d_out).

__global__ void k_gemm(const float* __restrict__ seq, const float* __restrict__ W,
                       float* __restrict__ P, float* __restrict__ Tt) {
    __shared__ float Stile[64 * 65];   // [c][n] padded
    __shared__ float Wl[2 * 16 * 64];  // [k][o_local][c]
    __shared__ float Ttile[64 * 17];   // [n][o_local] padded

    const int n0 = blockIdx.x * 64;
    const int o0 = blockIdx.y * 16;
    const int t  = threadIdx.x;
    const int n_l = t & 63;
    const int tg  = t >> 6;  // 0..3

    // Stage seq tile [64c][64n], coalesced along n.
    #pragma unroll
    for (int j = 0; j < 16; ++j) {
        int c = tg + 4 * j;
        Stile[c * 65 + n_l] = seq[c * N_NODES + n0 + n_l];
    }
    // Stage W slice: Wl[k*1024 + ol*64 + c] = W[(o0+ol)*128 + c*2 + k]
    #pragma unroll
    for (int j = 0; j < 8; ++j) {
        int e  = t + 256 * j;        // 0..2047
        int k  = e >> 10;
        int ol = (e >> 6) & 15;
        int c  = e & 63;
        Wl[e] = W[(o0 + ol) * 128 + c * 2 + k];
    }
    __syncthreads();

    float ap[4] = {0.f, 0.f, 0.f, 0.f};
    float at[4] = {0.f, 0.f, 0.f, 0.f};
    for (int c = 0; c < 64; ++c) {
        float s = Stile[c * 65 + n_l];
        #pragma unroll
        for (int i = 0; i < 4; ++i) {
            int ol = tg * 4 + i;
            ap[i] += Wl[ol * 64 + c] * s;          // k = 0
            at[i] += Wl[1024 + ol * 64 + c] * s;   // k = 1
        }
    }
    // P write: coalesced along n.
    #pragma unroll
    for (int i = 0; i < 4; ++i) {
        int o = o0 + tg * 4 + i;
        P[o * N_NODES + n0 + n_l] = ap[i];
    }
    // Transpose at[] through LDS, write Tt[n][o] coalesced-ish (64B segments).
    #pragma unroll
    for (int i = 0; i < 4; ++i) {
        Ttile[n_l * 17 + tg * 4 + i] = at[i];
    }
    __syncthreads();
    #pragma unroll
    for (int j = 0; j < 4; ++j) {
        int oc = t & 15;
        int nr = (t >> 4) + 16 * j;
        Tt[(n0 + nr) * C_DIM + o0 + oc] = Ttile[nr * 17 + oc];
    }
}

__global__ void k_scatter(const int* __restrict__ idx, const float* __restrict__ Tt,
                          float* __restrict__ outT, int* __restrict__ cnt) {
    const int t = threadIdx.x;
    const int e = blockIdx.x * 4 + (t >> 6);
    const int o = t & 63;
    const int u = idx[2 * e];
    const int v = idx[2 * e + 1];
    float val = Tt[v * C_DIM + o];
    unsafeAtomicAdd(&outT[u * C_DIM + o], val);
    if (o == 0) atomicAdd(&cnt[u], 1);
}

__global__ void k_final(const float* __restrict__ outT, const int* __restrict__ cnt,
                        float* __restrict__ out) {
    __shared__ float Atile[64 * 65];
    const int n0 = blockIdx.x * 64;
    const int t  = threadIdx.x;
    const int o  = t & 63;
    const int r4 = t >> 6;
    // Read outT [n][o] coalesced along o into padded LDS tile.
    #pragma unroll
    for (int j = 0; j < 16; ++j) {
        int n = r4 + 4 * j;
        Atile[n * 65 + o] = outT[(n0 + n) * C_DIM + o];
    }
    __syncthreads();
    const int n_l = t & 63;
    #pragma unroll
    for (int j = 0; j < 16; ++j) {
        int o2 = r4 + 4 * j;
        size_t gi = (size_t)o2 * N_NODES + n0 + n_l;
        float p = out[gi];                    // P (stored in d_out by k_gemm)
        float cn = (float)cnt[n0 + n_l];
        out[gi] = Atile[n_l * 65 + o2] + cn * p;
    }
}

extern "C" void kernel_launch(void* const* d_in, const int* in_sizes, int n_in,
                              void* d_out, int out_size, void* d_ws, size_t ws_size,
                              hipStream_t stream) {
    const float* seq = (const float*)d_in[0];
    const int*   idx = (const int*)d_in[1];
    const float* W   = (const float*)d_in[2];
    float* out = (float*)d_out;

    // Workspace layout: Tt [N*64 f32] | outT [N*64 f32] | cnt [N i32]  (~8.1 MB)
    float* Tt   = (float*)d_ws;
    float* outT = Tt + (size_t)N_NODES * C_DIM;
    int*   cnt  = (int*)(outT + (size_t)N_NODES * C_DIM);

    // Zero accumulator + histogram (ws is poisoned before every launch).
    hipMemsetAsync(outT, 0, (size_t)N_NODES * C_DIM * sizeof(float) + N_NODES * sizeof(int), stream);

    k_gemm<<<dim3(N_NODES / 64, C_DIM / 16), 256, 0, stream>>>(seq, W, out, Tt);
    k_scatter<<<M_EDGES / 4, 256, 0, stream>>>(idx, Tt, outT, cnt);
    k_final<<<N_NODES / 64, 256, 0, stream>>>(outT, cnt, out);
}

// Round 2
// 156.232 us; speedup vs baseline: 1.3472x; 1.3472x over previous
//
#include <hip/hip_runtime.h>
#include <hip/hip_bf16.h>

// Problem constants: B=1, C=64 in/out, N_NODES=16384, TWO_M=1048576 -> M=524288 edges.
#define C_DIM 64
#define N_NODES 16384
#define M_EDGES 524288

// out[:,n] = cnt[n] * (W0@seq)[:,n] + sum_{edges m with u_m==n} (W1@seq)[:, v_m]
// K1 k_gemm : P = W0@seq (into d_out, [o][n]) and Tt = (W1@seq)^T ([n][o]).
// K2 k_count: histogram cnt[u]  (int atomics, 64x fewer than the old fp32 scatter).
// K3 k_scan : exclusive prefix sum cnt -> rowstart (single block).
// K4 k_fill : CSR edge list  elist[rowstart[u]+cursor[u]++] = v.
// K5 k_gather: per-node gather-sum of Tt rows (atomic-free, L2-resident) + fused
//              transpose epilogue out[o][n] = gather + cnt[n]*P[o][n].

__global__ void k_gemm(const float* __restrict__ seq, const float* __restrict__ W,
                       float* __restrict__ P, float* __restrict__ Tt) {
    __shared__ float Stile[64 * 65];   // [c][n] padded
    __shared__ float Wl[2 * 16 * 64];  // [k][o_local][c]
    __shared__ float Ttile[64 * 17];   // [n][o_local] padded

    const int n0 = blockIdx.x * 64;
    const int o0 = blockIdx.y * 16;
    const int t  = threadIdx.x;
    const int n_l = t & 63;
    const int tg  = t >> 6;  // 0..3

    #pragma unroll
    for (int j = 0; j < 16; ++j) {
        int c = tg + 4 * j;
        Stile[c * 65 + n_l] = seq[c * N_NODES + n0 + n_l];
    }
    #pragma unroll
    for (int j = 0; j < 8; ++j) {
        int e  = t + 256 * j;        // 0..2047
        int k  = e >> 10;
        int ol = (e >> 6) & 15;
        int c  = e & 63;
        Wl[e] = W[(o0 + ol) * 128 + c * 2 + k];
    }
    __syncthreads();

    float ap[4] = {0.f, 0.f, 0.f, 0.f};
    float at[4] = {0.f, 0.f, 0.f, 0.f};
    for (int c = 0; c < 64; ++c) {
        float s = Stile[c * 65 + n_l];
        #pragma unroll
        for (int i = 0; i < 4; ++i) {
            int ol = tg * 4 + i;
            ap[i] += Wl[ol * 64 + c] * s;          // k = 0
            at[i] += Wl[1024 + ol * 64 + c] * s;   // k = 1
        }
    }
    #pragma unroll
    for (int i = 0; i < 4; ++i) {
        int o = o0 + tg * 4 + i;
        P[o * N_NODES + n0 + n_l] = ap[i];
    }
    #pragma unroll
    for (int i = 0; i < 4; ++i) {
        Ttile[n_l * 17 + tg * 4 + i] = at[i];
    }
    __syncthreads();
    #pragma unroll
    for (int j = 0; j < 4; ++j) {
        int oc = t & 15;
        int nr = (t >> 4) + 16 * j;
        Tt[(n0 + nr) * C_DIM + o0 + oc] = Ttile[nr * 17 + oc];
    }
}

__global__ void k_count(const int* __restrict__ idx, int* __restrict__ cnt) {
    const int e = blockIdx.x * 256 + threadIdx.x;
    int2 p = ((const int2*)idx)[e];
    atomicAdd(&cnt[p.x], 1);
}

__global__ void k_scan(const int* __restrict__ cnt, int* __restrict__ rowstart) {
    __shared__ int wsum[16];
    const int t = threadIdx.x;        // 1024 threads
    const int lane = t & 63, wv = t >> 6;
    int local[16];
    int s = 0;
    #pragma unroll
    for (int i = 0; i < 16; ++i) { local[i] = cnt[t * 16 + i]; s += local[i]; }
    int x = s;  // inclusive wave scan
    #pragma unroll
    for (int d = 1; d < 64; d <<= 1) {
        int y = __shfl_up(x, (unsigned)d);
        if (lane >= d) x += y;
    }
    if (lane == 63) wsum[wv] = x;
    __syncthreads();
    if (t == 0) {
        int acc = 0;
        #pragma unroll
        for (int i = 0; i < 16; ++i) { int v = wsum[i]; wsum[i] = acc; acc += v; }
    }
    __syncthreads();
    int base = wsum[wv] + (x - s);    // exclusive prefix of this thread's chunk
    #pragma unroll
    for (int i = 0; i < 16; ++i) { rowstart[t * 16 + i] = base; base += local[i]; }
}

__global__ void k_fill(const int* __restrict__ idx, const int* __restrict__ rowstart,
                       int* __restrict__ cursor, int* __restrict__ elist) {
    const int e = blockIdx.x * 256 + threadIdx.x;
    int2 p = ((const int2*)idx)[e];
    int pos = atomicAdd(&cursor[p.x], 1);
    elist[rowstart[p.x] + pos] = p.y;
}

__global__ __launch_bounds__(256)
void k_gather(const int* __restrict__ rowstart, const int* __restrict__ cnt,
              const int* __restrict__ elist, const float* __restrict__ Tt,
              float* __restrict__ out) {
    __shared__ float Atile[32 * 65];  // [n_local][o] padded
    const int n0 = blockIdx.x * 32;
    const int t  = threadIdx.x;
    const int o  = t & 63;
    const int wv = t >> 6;            // 0..3

    #pragma unroll
    for (int s = 0; s < 8; ++s) {
        const int nl = wv + 4 * s;
        const int n  = n0 + nl;
        const int base = rowstart[n];
        const int d    = cnt[n];
        float acc = 0.f;
        for (int jb = 0; jb < d; jb += 64) {
            const int chunk = min(64, d - jb);
            int vv = 0;
            if (o < chunk) vv = elist[base + jb + o];
            int j = 0;
            for (; j + 4 <= chunk; j += 4) {
                int v0 = __shfl(vv, j);
                int v1 = __shfl(vv, j + 1);
                int v2 = __shfl(vv, j + 2);
                int v3 = __shfl(vv, j + 3);
                float a0 = Tt[v0 * C_DIM + o];
                float a1 = Tt[v1 * C_DIM + o];
                float a2 = Tt[v2 * C_DIM + o];
                float a3 = Tt[v3 * C_DIM + o];
                acc += a0; acc += a1; acc += a2; acc += a3;
            }
            for (; j < chunk; ++j) {
                int v = __shfl(vv, j);
                acc += Tt[v * C_DIM + o];
            }
        }
        Atile[nl * 65 + o] = acc;
    }
    __syncthreads();
    // Fused epilogue: out[o][n] = Atile[n][o] + cnt[n] * P[o][n]  (P lives in d_out)
    const int nl = t & 31;
    const int ob = t >> 5;            // 0..7
    const float cn = (float)cnt[n0 + nl];
    #pragma unroll
    for (int j = 0; j < 8; ++j) {
        int o2 = ob + 8 * j;
        size_t gi = (size_t)o2 * N_NODES + n0 + nl;
        float p = out[gi];
        out[gi] = Atile[nl * 65 + o2] + cn * p;
    }
}

extern "C" void kernel_launch(void* const* d_in, const int* in_sizes, int n_in,
                              void* d_out, int out_size, void* d_ws, size_t ws_size,
                              hipStream_t stream) {
    const float* seq = (const float*)d_in[0];
    const int*   idx = (const int*)d_in[1];
    const float* W   = (const float*)d_in[2];
    float* out = (float*)d_out;

    // ws layout: Tt [N*64 f32] | cnt [N] | cursor [N] | rowstart [N] | elist [M]  (~6.3 MB)
    float* Tt       = (float*)d_ws;
    int*   cnt      = (int*)(Tt + (size_t)N_NODES * C_DIM);
    int*   cursor   = cnt + N_NODES;
    int*   rowstart = cursor + N_NODES;
    int*   elist    = rowstart + N_NODES;

    // Zero cnt + cursor (adjacent, 128 KB total).
    hipMemsetAsync(cnt, 0, 2 * N_NODES * sizeof(int), stream);

    k_gemm<<<dim3(N_NODES / 64, C_DIM / 16), 256, 0, stream>>>(seq, W, out, Tt);
    k_count<<<M_EDGES / 256, 256, 0, stream>>>(idx, cnt);
    k_scan<<<1, 1024, 0, stream>>>(cnt, rowstart);
    k_fill<<<M_EDGES / 256, 256, 0, stream>>>(idx, rowstart, cursor, elist);
    k_gather<<<N_NODES / 32, 256, 0, stream>>>(rowstart, cnt, elist, Tt, out);
}